// Round 1
// baseline (409.077 us; speedup 1.0000x reference)
//
#include <hip/hip_runtime.h>
#include <hip/hip_bf16.h>

typedef __attribute__((ext_vector_type(8))) short short8;
typedef __attribute__((ext_vector_type(4))) float f32x4;

__device__ __forceinline__ unsigned pkbf(float a, float b) {
  __hip_bfloat162 h = __float22bfloat162_rn(make_float2(a, b));
  return *reinterpret_cast<unsigned*>(&h);
}

// ---------------- prep: ci = [Xc | cov] ----------------
__global__ __launch_bounds__(256) void prep_ci(
    const float* __restrict__ X, const float* __restrict__ cov,
    float* __restrict__ ci) {
  int i = blockIdx.x * 256 + threadIdx.x;
  if (i >= (512 * 4096) / 4) return;
  float4 x = ((const float4*)X)[i];
  float4 cv = ((const float4*)cov)[i];
  float4 xc, cm;
  xc.x = (x.x == x.x) ? x.x : 0.f; cm.x = (x.x == x.x) ? cv.x : 0.f;
  xc.y = (x.y == x.y) ? x.y : 0.f; cm.y = (x.y == x.y) ? cv.y : 0.f;
  xc.z = (x.z == x.z) ? x.z : 0.f; cm.z = (x.z == x.z) ? cv.z : 0.f;
  xc.w = (x.w == x.w) ? x.w : 0.f; cm.w = (x.w == x.w) ? cv.w : 0.f;
  int b = i >> 10;
  int m4 = (i & 1023) << 2;
  *(float4*)&ci[(long)b * 8192 + m4] = xc;
  *(float4*)&ci[(long)b * 8192 + 4096 + m4] = cm;
}

// ------------- fp32 GEMM: ci @ [W1|Wm1], split-K=16 -> partials -------------
__global__ __launch_bounds__(256) void gemm1(
    const float* __restrict__ ci, const float* __restrict__ W1,
    const float* __restrict__ Wm1, float* __restrict__ part) {
  __shared__ float As[8][128];
  __shared__ float Bs[8][128];
  int bid = blockIdx.x;
  int mt = bid & 3, nt = (bid >> 2) & 3, ks = bid >> 4;
  int row0 = mt * 128, n0 = nt * 128, k0 = ks * 512;
  const float* bsrc = (n0 < 256) ? (W1 + n0) : (Wm1 + (n0 - 256));
  int t = threadIdx.x;
  int tx = t & 15, ty = t >> 4;
  int ar = t >> 1, ak = (t & 1) * 4;
  int bk = t >> 5, bn = (t & 31) * 4;
  float acc[8][8] = {};
  const float* aptr = ci + (long)(row0 + ar) * 8192 + k0 + ak;
  const float* bptr = bsrc + (long)(k0 + bk) * 256 + bn;
  float4 av = *(const float4*)aptr;
  float4 bv = *(const float4*)bptr;
  for (int kk0 = 8; kk0 <= 512; kk0 += 8) {
    __syncthreads();
    As[ak + 0][ar] = av.x; As[ak + 1][ar] = av.y;
    As[ak + 2][ar] = av.z; As[ak + 3][ar] = av.w;
    *(float4*)&Bs[bk][bn] = bv;
    __syncthreads();
    if (kk0 < 512) {
      av = *(const float4*)(aptr + kk0);
      bv = *(const float4*)(bptr + (long)kk0 * 256);
    }
#pragma unroll
    for (int kk = 0; kk < 8; ++kk) {
      float4 a0 = *(float4*)&As[kk][ty * 8];
      float4 a1 = *(float4*)&As[kk][ty * 8 + 4];
      float4 b0 = *(float4*)&Bs[kk][tx * 8];
      float4 b1 = *(float4*)&Bs[kk][tx * 8 + 4];
      float aa[8] = {a0.x, a0.y, a0.z, a0.w, a1.x, a1.y, a1.z, a1.w};
      float bb[8] = {b0.x, b0.y, b0.z, b0.w, b1.x, b1.y, b1.z, b1.w};
#pragma unroll
      for (int i = 0; i < 8; i++)
#pragma unroll
        for (int j = 0; j < 8; j++) acc[i][j] += aa[i] * bb[j];
    }
  }
  float* P = part + ((long)ks * 512 + row0) * 512 + n0;
#pragma unroll
  for (int i = 0; i < 8; i++)
#pragma unroll
    for (int j = 0; j < 8; j += 4) {
      float4 vv = {acc[i][j], acc[i][j + 1], acc[i][j + 2], acc[i][j + 3]};
      *(float4*)&P[(ty * 8 + i) * 512 + tx * 8 + j] = vv;
    }
}

// ---------------- block reduce helper ----------------
template <int NT>
__device__ __forceinline__ float block_sum(float v, float* red) {
#pragma unroll
  for (int o = 32; o > 0; o >>= 1) v += __shfl_down(v, o, 64);
  int w = threadIdx.x >> 6;
  if ((threadIdx.x & 63) == 0) red[w] = v;
  __syncthreads();
  float s = 0.f;
#pragma unroll
  for (int i = 0; i < NT / 64; ++i) s += red[i];
  __syncthreads();
  return s;
}

// ------------- reduce partials + LN + relu; h1 fp32, lh bf16 -------------
__global__ __launch_bounds__(256) void ln_dual(
    const float* __restrict__ part,
    const float* __restrict__ b1, const float* __restrict__ g1, const float* __restrict__ be1,
    const float* __restrict__ bm1, const float* __restrict__ gm, const float* __restrict__ bem,
    float* __restrict__ h1, ushort* __restrict__ lh) {
  __shared__ float red[4];
  int b = blockIdx.x >> 1, half = blockIdx.x & 1;
  int t = threadIdx.x;
  int n = half * 256 + t;
  float v = 0.f;
#pragma unroll
  for (int s = 0; s < 16; ++s) v += part[((long)s << 18) + b * 512 + n];
  v += half ? bm1[t] : b1[t];
  float mu = block_sum<256>(v, red) * (1.f / 256.f);
  float d = v - mu;
  float var = block_sum<256>(d * d, red) * (1.f / 256.f);
  float y = d / sqrtf(var + 1e-5f);
  y = y * (half ? gm[t] : g1[t]) + (half ? bem[t] : be1[t]);
  y = fmaxf(y, 0.f);
  if (half == 0) {
    h1[b * 256 + t] = y;
  } else {
    __hip_bfloat16 hb = __float2bfloat16(y);
    lh[b * 256 + t] = *reinterpret_cast<ushort*>(&hb);
  }
}

// ------------- est head: h1->h2->est->argmin idx -------------
__global__ __launch_bounds__(64) void est_head(
    const float* __restrict__ h1, const float* __restrict__ W2, const float* __restrict__ b2,
    const float* __restrict__ g2, const float* __restrict__ be2,
    const float* __restrict__ W3, const float* __restrict__ b3,
    const float* __restrict__ cg, float* __restrict__ est, int* __restrict__ idxb) {
  __shared__ float row[256];
  __shared__ float h2s[64];
  int b = blockIdx.x, t = threadIdx.x;
#pragma unroll
  for (int i = 0; i < 4; ++i) row[t + i * 64] = h1[b * 256 + t + i * 64];
  __syncthreads();
  float acc = b2[t];
  for (int k = 0; k < 256; ++k) acc += row[k] * W2[k * 64 + t];
  float s = acc;
#pragma unroll
  for (int o = 32; o > 0; o >>= 1) s += __shfl_xor(s, o, 64);
  float mu = s * (1.f / 64.f);
  float d = acc - mu;
  float q = d * d;
#pragma unroll
  for (int o = 32; o > 0; o >>= 1) q += __shfl_xor(q, o, 64);
  float var = q * (1.f / 64.f);
  float y = d / sqrtf(var + 1e-5f) * g2[t] + be2[t];
  h2s[t] = fmaxf(y, 0.f);
  __syncthreads();
  if (t < 16) {
    float a = b3[t];
#pragma unroll
    for (int k = 0; k < 64; ++k) a += h2s[k] * W3[k * 16 + t];
    float e = 1.f / (1.f + expf(-a));
    est[b * 16 + t] = e;
    float best = 1e30f; int bi = 0;
    for (int j = 0; j < 50; ++j) {
      float dd = fabsf(cg[t * 50 + j] - e);
      if (dd < best) { best = dd; bi = j; }
    }
    idxb[b * 16 + t] = bi;
  }
}

// ------------- MFMA GEMM M2: lh @ Wm2 -> sigmoid * dw -> mw -------------
__global__ __launch_bounds__(512, 2) void gemm_m2(
    const ushort* __restrict__ lh, const float* __restrict__ Wm2,
    const float* __restrict__ bm2, const int* __restrict__ idxb,
    const float* __restrict__ dist, float* __restrict__ mw) {
  __shared__ int4 AslRaw[2048];  // 256 rows x 64 k bf16 (32KB), swizzled
  __shared__ int4 BslRaw[1024];  // 128 n x 64 k bf16 (16KB), swizzled
  __shared__ int idxs[256];
  char* Asl = (char*)AslRaw;
  char* Bsl = (char*)BslRaw;
  int bid = blockIdx.x;
  int L = (bid & 7) * 128 + (bid >> 3);  // XCD swizzle, nwg=1024
  int nt = L >> 1, mt = L & 1;
  int b0 = mt * 256;
  long n0 = (long)nt * 128;
  int c = (int)(n0 >> 12);
  int t = threadIdx.x;
  int lane = t & 63, wid = t >> 6;
  int wr = wid >> 1, wc = wid & 1;  // 4x2 waves, wave tile 64x64

  for (int i = t; i < 256; i += 512) idxs[i] = idxb[(b0 + i) * 16 + c];

  f32x4 acc[4][4];
#pragma unroll
  for (int i = 0; i < 4; i++)
#pragma unroll
    for (int j = 0; j < 4; j++) acc[i][j] = f32x4{0.f, 0.f, 0.f, 0.f};

  int r = t & 255, h = t >> 8;
  int nn = t & 127, kg = t >> 7;

  for (int ks = 0; ks < 4; ++ks) {
    __syncthreads();
    {  // stage A (already bf16)
      const int4* src = (const int4*)(lh + (b0 + r) * 256 + ks * 64 + h * 32);
#pragma unroll
      for (int i = 0; i < 4; ++i) {
        int4 v = src[i];
        int off = r * 128 + ((h * 64 + i * 16) ^ ((r & 7) << 4));
        *(int4*)(Asl + off) = v;
      }
    }
    {  // stage B: fp32 column loads -> bf16, transposed [n][k]
      const float* src = Wm2 + (long)(ks * 64 + kg * 16) * 65536 + n0 + nn;
      float f[16];
#pragma unroll
      for (int j = 0; j < 16; ++j) f[j] = src[(long)j * 65536];
      unsigned p[8];
#pragma unroll
      for (int j = 0; j < 8; ++j) p[j] = pkbf(f[2 * j], f[2 * j + 1]);
      int off0 = nn * 128 + ((kg * 32) ^ ((nn & 7) << 4));
      int off1 = nn * 128 + ((kg * 32 + 16) ^ ((nn & 7) << 4));
      *(int4*)(Bsl + off0) = make_int4(p[0], p[1], p[2], p[3]);
      *(int4*)(Bsl + off1) = make_int4(p[4], p[5], p[6], p[7]);
    }
    __syncthreads();
#pragma unroll
    for (int kk = 0; kk < 2; ++kk) {
      int kbyte = kk * 64 + (lane >> 4) * 16;
      short8 af[4], bfr[4];
#pragma unroll
      for (int rb = 0; rb < 4; ++rb) {
        int rr = wr * 64 + rb * 16 + (lane & 15);
        af[rb] = *(const short8*)(Asl + rr * 128 + (kbyte ^ ((rr & 7) << 4)));
      }
#pragma unroll
      for (int cb = 0; cb < 4; ++cb) {
        int nc = wc * 64 + cb * 16 + (lane & 15);
        bfr[cb] = *(const short8*)(Bsl + nc * 128 + (kbyte ^ ((nc & 7) << 4)));
      }
#pragma unroll
      for (int rb = 0; rb < 4; ++rb)
#pragma unroll
        for (int cb = 0; cb < 4; ++cb)
          acc[rb][cb] = __builtin_amdgcn_mfma_f32_16x16x32_bf16(af[rb], bfr[cb], acc[rb][cb], 0, 0, 0);
    }
  }
  // epilogue: sigmoid(acc + bm2) * dist[c, idx[b,c], m] -> mw
#pragma unroll
  for (int rb = 0; rb < 4; ++rb) {
#pragma unroll
    for (int cb = 0; cb < 4; ++cb) {
      int nl = wc * 64 + cb * 16 + (lane & 15);
      long n = n0 + nl;
      float bias = bm2[n];
      long m = n & 4095;
#pragma unroll
      for (int reg = 0; reg < 4; ++reg) {
        int rl = wr * 64 + rb * 16 + (lane >> 4) * 4 + reg;
        float v = acc[rb][cb][reg] + bias;
        float sg = 1.f / (1.f + __expf(-v));
        float dwv = dist[((long)c * 50 + idxs[rl]) * 4096 + m];
        mw[(long)(b0 + rl) * 65536 + n] = sg * dwv;
      }
    }
  }
}

// ------------- MFMA GEMM F1: [Xc*mw | cov] @ Wf1, split-K atomic -------------
__global__ __launch_bounds__(512, 2) void gemm_f1(
    const float* __restrict__ mw, const float* __restrict__ ci,
    const float* __restrict__ Wf1, float* __restrict__ f1raw) {
  __shared__ int4 AslRaw[2048];  // 256 rows x 64 k bf16
  __shared__ int4 BslRaw[2048];  // 256 n x 64 k bf16
  char* Asl = (char*)AslRaw;
  char* Bsl = (char*)BslRaw;
  int bid = blockIdx.x;
  int L = (bid & 7) * 32 + (bid >> 3);  // XCD swizzle, nwg=256
  int kb = L >> 2;
  int mt = (L >> 1) & 1, nt = L & 1;
  int b0 = mt * 256, n0 = nt * 256;
  int kc0 = kb * 1088;
  int t = threadIdx.x;
  int lane = t & 63, wid = t >> 6;
  int wr = wid >> 2, wc = wid & 3;  // 2x4 waves, wave tile 128x64
  f32x4 acc[8][4];
#pragma unroll
  for (int i = 0; i < 8; i++)
#pragma unroll
    for (int j = 0; j < 4; j++) acc[i][j] = f32x4{0.f, 0.f, 0.f, 0.f};

  int r = t & 255, h = t >> 8;
  int nn = t & 255, kg = t >> 8;

  for (int s = 0; s < 17; ++s) {
    int k0 = kc0 + s * 64;
    __syncthreads();
    if (k0 < 65536) {  // A = Xc * mw
      const float4* w4 = (const float4*)(mw + (long)(b0 + r) * 65536 + k0 + h * 32);
      const float4* x4 = (const float4*)(ci + (long)(b0 + r) * 8192 + (k0 & 4095) + h * 32);
#pragma unroll
      for (int i2 = 0; i2 < 4; ++i2) {
        float4 wa = w4[i2 * 2], wb = w4[i2 * 2 + 1];
        float4 xa = x4[i2 * 2], xb = x4[i2 * 2 + 1];
        unsigned p0 = pkbf(wa.x * xa.x, wa.y * xa.y);
        unsigned p1 = pkbf(wa.z * xa.z, wa.w * xa.w);
        unsigned p2 = pkbf(wb.x * xb.x, wb.y * xb.y);
        unsigned p3 = pkbf(wb.z * xb.z, wb.w * xb.w);
        int off = r * 128 + ((h * 64 + i2 * 16) ^ ((r & 7) << 4));
        *(int4*)(Asl + off) = make_int4(p0, p1, p2, p3);
      }
    } else {  // A = cov
      const float4* x4 = (const float4*)(ci + (long)(b0 + r) * 8192 + 4096 + (k0 - 65536) + h * 32);
#pragma unroll
      for (int i2 = 0; i2 < 4; ++i2) {
        float4 xa = x4[i2 * 2], xb = x4[i2 * 2 + 1];
        unsigned p0 = pkbf(xa.x, xa.y);
        unsigned p1 = pkbf(xa.z, xa.w);
        unsigned p2 = pkbf(xb.x, xb.y);
        unsigned p3 = pkbf(xb.z, xb.w);
        int off = r * 128 + ((h * 64 + i2 * 16) ^ ((r & 7) << 4));
        *(int4*)(Asl + off) = make_int4(p0, p1, p2, p3);
      }
    }
    {  // stage B: Wf1 fp32 column loads -> bf16 transposed
      const float* src = Wf1 + (long)(k0 + kg * 32) * 512 + n0 + nn;
      float f[32];
#pragma unroll
      for (int j = 0; j < 32; ++j) f[j] = src[(long)j * 512];
      unsigned p[16];
#pragma unroll
      for (int j = 0; j < 16; ++j) p[j] = pkbf(f[2 * j], f[2 * j + 1]);
#pragma unroll
      for (int q = 0; q < 4; ++q) {
        int off = nn * 128 + ((kg * 64 + q * 16) ^ ((nn & 7) << 4));
        *(int4*)(Bsl + off) = make_int4(p[4 * q], p[4 * q + 1], p[4 * q + 2], p[4 * q + 3]);
      }
    }
    __syncthreads();
#pragma unroll
    for (int kk = 0; kk < 2; ++kk) {
      int kbyte = kk * 64 + (lane >> 4) * 16;
      short8 af[8], bfr[4];
#pragma unroll
      for (int rb = 0; rb < 8; ++rb) {
        int rr = wr * 128 + rb * 16 + (lane & 15);
        af[rb] = *(const short8*)(Asl + rr * 128 + (kbyte ^ ((rr & 7) << 4)));
      }
#pragma unroll
      for (int cb = 0; cb < 4; ++cb) {
        int nc = wc * 64 + cb * 16 + (lane & 15);
        bfr[cb] = *(const short8*)(Bsl + nc * 128 + (kbyte ^ ((nc & 7) << 4)));
      }
#pragma unroll
      for (int rb = 0; rb < 8; ++rb)
#pragma unroll
        for (int cb = 0; cb < 4; ++cb)
          acc[rb][cb] = __builtin_amdgcn_mfma_f32_16x16x32_bf16(af[rb], bfr[cb], acc[rb][cb], 0, 0, 0);
    }
  }
#pragma unroll
  for (int rb = 0; rb < 8; ++rb)
#pragma unroll
    for (int cb = 0; cb < 4; ++cb) {
      int nl = n0 + wc * 64 + cb * 16 + (lane & 15);
#pragma unroll
      for (int reg = 0; reg < 4; ++reg) {
        int bl = b0 + wr * 128 + rb * 16 + (lane >> 4) * 4 + reg;
        atomicAdd(&f1raw[bl * 512 + nl], acc[rb][cb][reg]);
      }
    }
}

// ------------- LN(f1raw + bf1) -> relu -------------
__global__ __launch_bounds__(512) void ln_f1(
    const float* __restrict__ f1raw, const float* __restrict__ bf1,
    const float* __restrict__ gf1, const float* __restrict__ bef1,
    float* __restrict__ f1ln) {
  __shared__ float red[8];
  int b = blockIdx.x, t = threadIdx.x;
  float v = f1raw[b * 512 + t] + bf1[t];
  float mu = block_sum<512>(v, red) * (1.f / 512.f);
  float d = v - mu;
  float var = block_sum<512>(d * d, red) * (1.f / 512.f);
  float y = d / sqrtf(var + 1e-5f) * gf1[t] + bef1[t];
  f1ln[b * 512 + t] = fmaxf(y, 0.f);
}

// ------------- f2 = relu(LN(f1ln @ Wf2 + bf2)) -------------
__global__ __launch_bounds__(256) void f2_head(
    const float* __restrict__ f1ln, const float* __restrict__ Wf2,
    const float* __restrict__ bf2, const float* __restrict__ gf2,
    const float* __restrict__ bef2, float* __restrict__ f2) {
  __shared__ float row[512];
  __shared__ float red[4];
  int b = blockIdx.x, t = threadIdx.x;
  row[t] = f1ln[b * 512 + t];
  row[t + 256] = f1ln[b * 512 + 256 + t];
  __syncthreads();
  float acc = bf2[t];
  for (int k = 0; k < 512; ++k) acc += row[k] * Wf2[k * 256 + t];
  float mu = block_sum<256>(acc, red) * (1.f / 256.f);
  float d = acc - mu;
  float var = block_sum<256>(d * d, red) * (1.f / 256.f);
  float y = d / sqrtf(var + 1e-5f) * gf2[t] + bef2[t];
  f2[b * 256 + t] = fmaxf(y, 0.f);
}

// ------------- logits -> softmax -> final -------------
__global__ __launch_bounds__(64) void final_head(
    const float* __restrict__ f2, const float* __restrict__ Wo,
    const float* __restrict__ bo, const float* __restrict__ est,
    float* __restrict__ fin) {
  __shared__ float row[256];
  int b = blockIdx.x, t = threadIdx.x;
#pragma unroll
  for (int i = 0; i < 4; ++i) row[t + i * 64] = f2[b * 256 + t + i * 64];
  __syncthreads();
  float lg = -1e30f;
  if (t < 16) {
    lg = bo[t];
    for (int k = 0; k < 256; ++k) lg += row[k] * Wo[k * 16 + t];
  }
  float m = lg;
#pragma unroll
  for (int o = 8; o > 0; o >>= 1) m = fmaxf(m, __shfl_xor(m, o, 64));
  float e = (t < 16) ? expf(lg - m) : 0.f;
  float ssum = e;
#pragma unroll
  for (int o = 8; o > 0; o >>= 1) ssum += __shfl_xor(ssum, o, 64);
  if (t < 16) fin[b * 16 + t] = 0.5f * (e / ssum + est[b * 16 + t]);
}

extern "C" void kernel_launch(void* const* d_in, const int* in_sizes, int n_in,
                              void* d_out, int out_size, void* d_ws, size_t ws_size,
                              hipStream_t stream) {
  const float* X = (const float*)d_in[0];
  const float* coverage = (const float*)d_in[1];
  const float* conc_grid = (const float*)d_in[2];
  const float* dist_table = (const float*)d_in[3];
  const float* W1 = (const float*)d_in[4];
  const float* b1 = (const float*)d_in[5];
  const float* g1 = (const float*)d_in[6];
  const float* be1 = (const float*)d_in[7];
  const float* W2 = (const float*)d_in[8];
  const float* b2 = (const float*)d_in[9];
  const float* g2 = (const float*)d_in[10];
  const float* be2 = (const float*)d_in[11];
  const float* W3 = (const float*)d_in[12];
  const float* b3 = (const float*)d_in[13];
  const float* Wm1 = (const float*)d_in[14];
  const float* bm1 = (const float*)d_in[15];
  const float* gm = (const float*)d_in[16];
  const float* bem = (const float*)d_in[17];
  const float* Wm2 = (const float*)d_in[18];
  const float* bm2 = (const float*)d_in[19];
  const float* Wf1 = (const float*)d_in[20];
  const float* bf1 = (const float*)d_in[21];
  const float* gf1 = (const float*)d_in[22];
  const float* bef1 = (const float*)d_in[23];
  const float* Wf2 = (const float*)d_in[24];
  const float* bf2 = (const float*)d_in[25];
  const float* gf2 = (const float*)d_in[26];
  const float* bef2 = (const float*)d_in[27];
  const float* Wo = (const float*)d_in[28];
  const float* bo = (const float*)d_in[29];

  float* out_final = (float*)d_out;
  float* out_est = out_final + 8192;
  float* out_mw = out_final + 16384;

  char* ws = (char*)d_ws;
  float* ci = (float*)(ws);                       // 16.8 MB
  float* part = (float*)(ws + 16777216);          // 16 MB (16 x 512 x 512)
  float* h1 = (float*)(ws + 33554432);            // 512 KB
  ushort* lh = (ushort*)(ws + 34078720);          // 256 KB bf16
  int* idxb = (int*)(ws + 34340864);              // 32 KB
  float* f1raw = (float*)(ws + 34373632);         // 1 MB
  float* f1ln = (float*)(ws + 35422208);          // 1 MB
  float* f2 = (float*)(ws + 36470784);            // 512 KB

  prep_ci<<<2048, 256, 0, stream>>>(X, coverage, ci);
  hipMemsetAsync(f1raw, 0, 512 * 512 * 4, stream);
  gemm1<<<256, 256, 0, stream>>>(ci, W1, Wm1, part);
  ln_dual<<<1024, 256, 0, stream>>>(part, b1, g1, be1, bm1, gm, bem, h1, lh);
  est_head<<<512, 64, 0, stream>>>(h1, W2, b2, g2, be2, W3, b3, conc_grid, out_est, idxb);
  gemm_m2<<<1024, 512, 0, stream>>>(lh, Wm2, bm2, idxb, dist_table, out_mw);
  gemm_f1<<<256, 512, 0, stream>>>(out_mw, ci, Wf1, f1raw);
  ln_f1<<<512, 512, 0, stream>>>(f1raw, bf1, gf1, bef1, f1ln);
  f2_head<<<512, 256, 0, stream>>>(f1ln, Wf2, bf2, gf2, bef2, f2);
  final_head<<<512, 64, 0, stream>>>(f2, Wo, bo, out_est, out_final);
}